// Round 4
// baseline (425.319 us; speedup 1.0000x reference)
//
#include <hip/hip_runtime.h>

#define NUM_IDS 65
#define EDIM 32
#define NSUM (NUM_IDS * EDIM)      // 2080 per-label-dim sums
#define NTOT (NSUM + NUM_IDS)      // 2145 = sums + counts
#define LPAD 33                    // padded row for LDS bank randomization

// ws layout (float offsets)
#define WS_MEANS   0               // 2080
#define WS_COEF    2080            // 65
#define WS_SUMS    2145            // 2145 (2080 sums then 65 counts)
#define WS_PUSH    4290
#define WS_REG     4291
#define WS_CF      4292
#define WS_C       4293
#define WS_PULLACC 4294
#define WS_PART    4352            // per-block partials [nb1][NTOT]

__global__ void k0_zero(float* __restrict__ ws) {
    int i = blockIdx.x * 256 + threadIdx.x;
    if (i < NTOT) ws[WS_SUMS + i] = 0.f;
}

// Pass 1: per-block LDS segment reduction. 8 threads per point, float4 each.
__global__ __launch_bounds__(512) void k1_reduce(const float4* __restrict__ emb4,
                                                 const int* __restrict__ lab,
                                                 float* __restrict__ ws,
                                                 int M, int nb1, int atomic_mode) {
    __shared__ float ls[NUM_IDS * LPAD + NUM_IDS];  // padded sums + counts
    const int t = threadIdx.x;
    for (int j = t; j < NUM_IDS * LPAD + NUM_IDS; j += 512) ls[j] = 0.f;
    __syncthreads();

    const int c = t & 7;            // which float4 chunk of the 32-dim row
    const int stride = nb1 * 64;    // 512 threads / 8 = 64 points per block-iter
    for (int p = blockIdx.x * 64 + (t >> 3); p < M; p += stride) {
        int L = lab[p];
        if (L > 0) {
            float4 v = emb4[(size_t)p * 8 + c];
            int base = L * LPAD + c * 4;
            atomicAdd(&ls[base + 0], v.x);
            atomicAdd(&ls[base + 1], v.y);
            atomicAdd(&ls[base + 2], v.z);
            atomicAdd(&ls[base + 3], v.w);
            if (c == 0) atomicAdd(&ls[NUM_IDS * LPAD + L], 1.f);
        }
    }
    __syncthreads();

    if (atomic_mode) {
        for (int j = t; j < NTOT; j += 512) {
            float v = (j < NSUM) ? ls[(j >> 5) * LPAD + (j & 31)]
                                 : ls[NUM_IDS * LPAD + (j - NSUM)];
            if (v != 0.f) atomicAdd(&ws[WS_SUMS + j], v);
        }
    } else {
        float* part = ws + WS_PART + (size_t)blockIdx.x * NTOT;
        for (int j = t; j < NTOT; j += 512) {
            float v = (j < NSUM) ? ls[(j >> 5) * LPAD + (j & 31)]
                                 : ls[NUM_IDS * LPAD + (j - NSUM)];
            part[j] = v;
        }
    }
}

// Reduce per-block partials: one block per output element j.
__global__ __launch_bounds__(256) void k2_reduce_partials(float* __restrict__ ws, int nb1) {
    const int j = blockIdx.x;       // 0..NTOT-1
    const int t = threadIdx.x;
    const float* part = ws + WS_PART;
    float acc = 0.f;
    for (int b = t; b < nb1; b += 256) acc += part[(size_t)b * NTOT + j];
    __shared__ float red[256];
    red[t] = acc;
    __syncthreads();
    for (int s = 128; s > 0; s >>= 1) {
        if (t < s) red[t] += red[t + s];
        __syncthreads();
    }
    if (t == 0) ws[WS_SUMS + j] = red[0];
}

// Means, present mask, C, push loss, reg loss, coef; zero pull accumulator.
__global__ __launch_bounds__(256) void k3_finalize(float* __restrict__ ws) {
    __shared__ float lmean[NUM_IDS * LPAD];
    __shared__ float lcnt[NUM_IDS];
    __shared__ int   lpres[NUM_IDS];
    __shared__ float red[256];
    __shared__ float red2[256];
    const int t = threadIdx.x;
    const float* sg = ws + WS_SUMS;

    if (t < NUM_IDS) {
        float cv = sg[NSUM + t];
        lcnt[t] = cv;
        lpres[t] = (t > 0 && cv > 0.f) ? 1 : 0;
    }
    __syncthreads();

    for (int j = t; j < NSUM; j += 256) {
        int cc = j >> 5, e = j & 31;
        float m = sg[j] / fmaxf(lcnt[cc], 1.f);
        ws[WS_MEANS + j] = m;
        lmean[cc * LPAD + e] = m;
    }
    if (t < NUM_IDS) ws[WS_COEF + t] = lpres[t] ? (1.f / fmaxf(lcnt[t], 1.f)) : 0.f;
    __syncthreads();

    // Push: 65*64/2 = 2080 unordered pairs.
    float psum = 0.f;
    for (int pi = t; pi < 2080; pi += 256) {
        int i = 0, rem = pi;
        while (rem >= NUM_IDS - 1 - i) { rem -= NUM_IDS - 1 - i; ++i; }
        int jj = i + 1 + rem;
        if (lpres[i] && lpres[jj]) {
            float d2 = 0.f;
            #pragma unroll
            for (int e = 0; e < EDIM; ++e) {
                float d = lmean[i * LPAD + e] - lmean[jj * LPAD + e];
                d2 += d * d;
            }
            float pd = sqrtf(d2);
            float h = fmaxf(2.0f * 1.5f - pd, 0.f);  // 2*DELTA_PUSH = 3.0
            psum += h * h;
        }
    }
    // Reg: norm of present means.
    float rsum = 0.f;
    if (t < NUM_IDS && lpres[t]) {
        float m2 = 0.f;
        #pragma unroll
        for (int e = 0; e < EDIM; ++e) { float m = lmean[t * LPAD + e]; m2 += m * m; }
        rsum = sqrtf(m2);
    }
    red[t] = psum; red2[t] = rsum;
    __syncthreads();
    for (int s = 128; s > 0; s >>= 1) {
        if (t < s) { red[t] += red[t + s]; red2[t] += red2[t + s]; }
        __syncthreads();
    }
    if (t == 0) {
        int C = 0;
        for (int cc = 1; cc < NUM_IDS; ++cc) C += lpres[cc];
        float Cf = fmaxf((float)C, 1.f);
        long np = (long)C * (C - 1) / 2;
        ws[WS_PUSH] = (np > 0) ? red[0] / (float)np : 0.f;
        ws[WS_REG]  = red2[0] / Cf;
        ws[WS_CF]   = Cf;
        ws[WS_C]    = (float)C;
        ws[WS_PULLACC] = 0.f;
    }
}

// Pass 2: hinged pull distances; per-block scalar contribution.
__global__ __launch_bounds__(256) void k4_pull(const float4* __restrict__ emb4,
                                               const int* __restrict__ lab,
                                               float* __restrict__ ws,
                                               int M, int nb4) {
    __shared__ float lmean[NUM_IDS * LPAD];
    __shared__ float lcoef[NUM_IDS];
    __shared__ float lpull[NUM_IDS];
    __shared__ float red[NUM_IDS];
    const int t = threadIdx.x;
    for (int j = t; j < NSUM; j += 256) lmean[(j >> 5) * LPAD + (j & 31)] = ws[WS_MEANS + j];
    if (t < NUM_IDS) { lcoef[t] = ws[WS_COEF + t]; lpull[t] = 0.f; }
    __syncthreads();

    const int c = t & 7;
    const int stride = nb4 * 32;   // 256 threads / 8 = 32 points per block-iter
    for (int p = blockIdx.x * 32 + (t >> 3); p < M; p += stride) {
        int L = lab[p];
        float d2 = 0.f;
        if (L > 0) {
            float4 v = emb4[(size_t)p * 8 + c];
            int base = L * LPAD + c * 4;
            float dx = v.x - lmean[base + 0];
            float dy = v.y - lmean[base + 1];
            float dz = v.z - lmean[base + 2];
            float dw = v.w - lmean[base + 3];
            d2 = dx * dx + dy * dy + dz * dz + dw * dw;
        }
        d2 += __shfl_xor(d2, 1);
        d2 += __shfl_xor(d2, 2);
        d2 += __shfl_xor(d2, 4);
        if (c == 0 && L > 0 && d2 > 0.f) {
            float dist = sqrtf(d2);
            float h = fmaxf(dist - 0.5f, 0.f);   // DELTA_PULL = 0.5
            atomicAdd(&lpull[L], h * h);
        }
    }
    __syncthreads();
    if (t < NUM_IDS) red[t] = lpull[t] * lcoef[t];
    __syncthreads();
    if (t == 0) {
        float s = 0.f;
        for (int cc = 1; cc < NUM_IDS; ++cc) s += red[cc];
        atomicAdd(&ws[WS_PULLACC], s);
    }
}

__global__ void k5_final(const float* __restrict__ ws, float* __restrict__ out) {
    if (threadIdx.x == 0) {
        float C = ws[WS_C];
        float total = 0.f;
        if (C > 0.f) {
            total = ws[WS_PULLACC] / ws[WS_CF]   // ALPHA = 1
                  + ws[WS_PUSH]                  // BETA = 1
                  + 0.001f * ws[WS_REG];         // GAMMA = 0.001
        }
        out[0] = total;
    }
}

extern "C" void kernel_launch(void* const* d_in, const int* in_sizes, int n_in,
                              void* d_out, int out_size, void* d_ws, size_t ws_size,
                              hipStream_t stream) {
    const float4* emb4 = (const float4*)d_in[0];
    const int* lab = (const int*)d_in[1];
    float* ws = (float*)d_ws;
    float* out = (float*)d_out;
    const int M = in_sizes[1];

    // Size pass-1 grid to available workspace; fall back to global atomics if tiny.
    long ws_floats = (long)(ws_size / 4);
    long avail = ws_floats - WS_PART - 64;
    int nb1 = (int)(avail / NTOT);
    if (nb1 > 1024) nb1 = 1024;
    int atomic_mode = (nb1 < 8) ? 1 : 0;
    if (atomic_mode) {
        nb1 = 1024;
        k0_zero<<<dim3(9), dim3(256), 0, stream>>>(ws);
    }

    k1_reduce<<<dim3(nb1), dim3(512), 0, stream>>>(emb4, lab, ws, M, nb1, atomic_mode);
    if (!atomic_mode)
        k2_reduce_partials<<<dim3(NTOT), dim3(256), 0, stream>>>(ws, nb1);
    k3_finalize<<<dim3(1), dim3(256), 0, stream>>>(ws);
    const int nb4 = 2048;
    k4_pull<<<dim3(nb4), dim3(256), 0, stream>>>(emb4, lab, ws, M, nb4);
    k5_final<<<dim3(1), dim3(64), 0, stream>>>(ws, out);
}

// Round 5
// 195.833 us; speedup vs baseline: 2.1718x; 2.1718x over previous
//
#include <hip/hip_runtime.h>

#define NUM_IDS 65
#define EDIM 32
#define NSUM (NUM_IDS * EDIM)      // 2080 per-label-dim sums
#define NTOT (NSUM + NUM_IDS)      // 2145 = sums + counts
#define LPAD 33                    // padded row for k3/k4 LDS tiles
#define ROWS 34                    // k1 row: 32 sums + count + pad; 34*4B=136B keeps 8B align
#define COPYSZ 2212                // 65*34=2210 -> pad to even for 8B-aligned copies

// ws layout (float offsets)
#define WS_MEANS   0               // 2080
#define WS_COEF    2080            // 65
#define WS_SUMS    2145            // 2145 (2080 sums then 65 counts)
#define WS_PUSH    4290
#define WS_REG     4291
#define WS_CF      4292
#define WS_C       4293
#define WS_PULLACC 4294
#define WS_PART    4352            // per-block partials [nb1][NTOT]

__global__ void k0_zero(float* __restrict__ ws) {
    int i = blockIdx.x * 256 + threadIdx.x;
    if (i < NTOT) ws[WS_SUMS + i] = 0.f;
}

// Pass 1: wave-private non-atomic LDS segment reduction.
// 16 lanes per point (float2 each), 4 points per wave, 4 waves per block.
// Intra-wave label collisions detected via shuffles; serialized only then.
__global__ __launch_bounds__(256) void k1_reduce(const float2* __restrict__ emb2,
                                                 const int* __restrict__ lab,
                                                 float* __restrict__ ws,
                                                 int M, int nb1, int atomic_mode) {
    __shared__ float ls[4 * COPYSZ];   // 4 wave-private copies, 35.4 KB
    const int t = threadIdx.x;
    for (int j = t; j < 4 * COPYSZ; j += 256) ls[j] = 0.f;
    __syncthreads();

    const int wave = t >> 6;
    const int lane = t & 63;
    const int s = lane >> 4;           // point slot 0..3 within wave
    const int c = lane & 15;           // float2 chunk 0..15 (dims 2c,2c+1)
    float* my = ls + wave * COPYSZ;

    const long stride = (long)nb1 * 16;   // 16 points per block-iter
    for (long p = (long)blockIdx.x * 16 + wave * 4 + s; p < M; p += stride) {
        const int L = lab[p];
        const bool act = (L > 0);
        float2 v = make_float2(0.f, 0.f);
        if (act) v = emb2[p * 16 + c];

        // unique negative keys for inactive slots so they never "collide"
        int key = act ? L : (-1 - s);
        int k0 = __shfl(key, 0), k1 = __shfl(key, 16);
        int k2 = __shfl(key, 32), k3 = __shfl(key, 48);
        bool col = (k0 == k1) | (k0 == k2) | (k0 == k3) |
                   (k1 == k2) | (k1 == k3) | (k2 == k3);

        const int off = L * ROWS + 2 * c;
        if (!col) {
            // all 4 slots have distinct labels: full-wave parallel RMW
            if (act) {
                float2 o = *(float2*)(my + off);
                o.x += v.x; o.y += v.y;
                *(float2*)(my + off) = o;
                if (c == 0) my[L * ROWS + 32] += 1.f;   // count
            }
        } else {
            // rare (~9%): serialize the 4 slots (DS ops are in-order per wave)
            #pragma unroll
            for (int ss = 0; ss < 4; ++ss) {
                if (s == ss && act) {
                    float2 o = *(float2*)(my + off);
                    o.x += v.x; o.y += v.y;
                    *(float2*)(my + off) = o;
                    if (c == 0) my[L * ROWS + 32] += 1.f;
                }
            }
        }
    }
    __syncthreads();

    // Flush: sum the 4 wave copies -> per-block partials (or global atomics).
    for (int j = t; j < NTOT; j += 256) {
        int off = (j < NSUM) ? ((j >> 5) * ROWS + (j & 31))
                             : ((j - NSUM) * ROWS + 32);
        float v = ls[off] + ls[COPYSZ + off] + ls[2 * COPYSZ + off] + ls[3 * COPYSZ + off];
        if (atomic_mode) {
            if (v != 0.f) atomicAdd(&ws[WS_SUMS + j], v);
        } else {
            ws[WS_PART + (size_t)blockIdx.x * NTOT + j] = v;
        }
    }
}

// Reduce per-block partials: one block per output element j.
__global__ __launch_bounds__(256) void k2_reduce_partials(float* __restrict__ ws, int nb1) {
    const int j = blockIdx.x;       // 0..NTOT-1
    const int t = threadIdx.x;
    const float* part = ws + WS_PART;
    float acc = 0.f;
    for (int b = t; b < nb1; b += 256) acc += part[(size_t)b * NTOT + j];
    __shared__ float red[256];
    red[t] = acc;
    __syncthreads();
    for (int s = 128; s > 0; s >>= 1) {
        if (t < s) red[t] += red[t + s];
        __syncthreads();
    }
    if (t == 0) ws[WS_SUMS + j] = red[0];
}

// Means, present mask, C, push loss, reg loss, coef; zero pull accumulator.
__global__ __launch_bounds__(256) void k3_finalize(float* __restrict__ ws) {
    __shared__ float lmean[NUM_IDS * LPAD];
    __shared__ float lcnt[NUM_IDS];
    __shared__ int   lpres[NUM_IDS];
    __shared__ float red[256];
    __shared__ float red2[256];
    const int t = threadIdx.x;
    const float* sg = ws + WS_SUMS;

    if (t < NUM_IDS) {
        float cv = sg[NSUM + t];
        lcnt[t] = cv;
        lpres[t] = (t > 0 && cv > 0.f) ? 1 : 0;
    }
    __syncthreads();

    for (int j = t; j < NSUM; j += 256) {
        int cc = j >> 5, e = j & 31;
        float m = sg[j] / fmaxf(lcnt[cc], 1.f);
        ws[WS_MEANS + j] = m;
        lmean[cc * LPAD + e] = m;
    }
    if (t < NUM_IDS) ws[WS_COEF + t] = lpres[t] ? (1.f / fmaxf(lcnt[t], 1.f)) : 0.f;
    __syncthreads();

    // Push: 65*64/2 = 2080 unordered pairs.
    float psum = 0.f;
    for (int pi = t; pi < 2080; pi += 256) {
        int i = 0, rem = pi;
        while (rem >= NUM_IDS - 1 - i) { rem -= NUM_IDS - 1 - i; ++i; }
        int jj = i + 1 + rem;
        if (lpres[i] && lpres[jj]) {
            float d2 = 0.f;
            #pragma unroll
            for (int e = 0; e < EDIM; ++e) {
                float d = lmean[i * LPAD + e] - lmean[jj * LPAD + e];
                d2 += d * d;
            }
            float pd = sqrtf(d2);
            float h = fmaxf(2.0f * 1.5f - pd, 0.f);  // 2*DELTA_PUSH = 3.0
            psum += h * h;
        }
    }
    // Reg: norm of present means.
    float rsum = 0.f;
    if (t < NUM_IDS && lpres[t]) {
        float m2 = 0.f;
        #pragma unroll
        for (int e = 0; e < EDIM; ++e) { float m = lmean[t * LPAD + e]; m2 += m * m; }
        rsum = sqrtf(m2);
    }
    red[t] = psum; red2[t] = rsum;
    __syncthreads();
    for (int s = 128; s > 0; s >>= 1) {
        if (t < s) { red[t] += red[t + s]; red2[t] += red2[t + s]; }
        __syncthreads();
    }
    if (t == 0) {
        int C = 0;
        for (int cc = 1; cc < NUM_IDS; ++cc) C += lpres[cc];
        float Cf = fmaxf((float)C, 1.f);
        long np = (long)C * (C - 1) / 2;
        ws[WS_PUSH] = (np > 0) ? red[0] / (float)np : 0.f;
        ws[WS_REG]  = red2[0] / Cf;
        ws[WS_CF]   = Cf;
        ws[WS_C]    = (float)C;
        ws[WS_PULLACC] = 0.f;
    }
}

// Pass 2: hinged pull distances; per-block scalar contribution.
__global__ __launch_bounds__(256) void k4_pull(const float4* __restrict__ emb4,
                                               const int* __restrict__ lab,
                                               float* __restrict__ ws,
                                               int M, int nb4) {
    __shared__ float lmean[NUM_IDS * LPAD];
    __shared__ float lcoef[NUM_IDS];
    __shared__ float lpull[NUM_IDS];
    __shared__ float red[NUM_IDS];
    const int t = threadIdx.x;
    for (int j = t; j < NSUM; j += 256) lmean[(j >> 5) * LPAD + (j & 31)] = ws[WS_MEANS + j];
    if (t < NUM_IDS) { lcoef[t] = ws[WS_COEF + t]; lpull[t] = 0.f; }
    __syncthreads();

    const int c = t & 7;
    const int stride = nb4 * 32;   // 256 threads / 8 = 32 points per block-iter
    for (int p = blockIdx.x * 32 + (t >> 3); p < M; p += stride) {
        int L = lab[p];
        float d2 = 0.f;
        if (L > 0) {
            float4 v = emb4[(size_t)p * 8 + c];
            int base = L * LPAD + c * 4;
            float dx = v.x - lmean[base + 0];
            float dy = v.y - lmean[base + 1];
            float dz = v.z - lmean[base + 2];
            float dw = v.w - lmean[base + 3];
            d2 = dx * dx + dy * dy + dz * dz + dw * dw;
        }
        d2 += __shfl_xor(d2, 1);
        d2 += __shfl_xor(d2, 2);
        d2 += __shfl_xor(d2, 4);
        if (c == 0 && L > 0 && d2 > 0.f) {
            float dist = sqrtf(d2);
            float h = fmaxf(dist - 0.5f, 0.f);   // DELTA_PULL = 0.5
            atomicAdd(&lpull[L], h * h);
        }
    }
    __syncthreads();
    if (t < NUM_IDS) red[t] = lpull[t] * lcoef[t];
    __syncthreads();
    if (t == 0) {
        float s = 0.f;
        for (int cc = 1; cc < NUM_IDS; ++cc) s += red[cc];
        atomicAdd(&ws[WS_PULLACC], s);
    }
}

__global__ void k5_final(const float* __restrict__ ws, float* __restrict__ out) {
    if (threadIdx.x == 0) {
        float C = ws[WS_C];
        float total = 0.f;
        if (C > 0.f) {
            total = ws[WS_PULLACC] / ws[WS_CF]   // ALPHA = 1
                  + ws[WS_PUSH]                  // BETA = 1
                  + 0.001f * ws[WS_REG];         // GAMMA = 0.001
        }
        out[0] = total;
    }
}

extern "C" void kernel_launch(void* const* d_in, const int* in_sizes, int n_in,
                              void* d_out, int out_size, void* d_ws, size_t ws_size,
                              hipStream_t stream) {
    const float2* emb2 = (const float2*)d_in[0];
    const float4* emb4 = (const float4*)d_in[0];
    const int* lab = (const int*)d_in[1];
    float* ws = (float*)d_ws;
    float* out = (float*)d_out;
    const int M = in_sizes[1];

    // Size pass-1 grid to available workspace; fall back to global atomics if tiny.
    long ws_floats = (long)(ws_size / 4);
    long avail = ws_floats - WS_PART - 64;
    int nb1 = (int)(avail / NTOT);
    if (nb1 > 1024) nb1 = 1024;
    int atomic_mode = (nb1 < 8) ? 1 : 0;
    if (atomic_mode) {
        nb1 = 1024;
        k0_zero<<<dim3(9), dim3(256), 0, stream>>>(ws);
    }

    k1_reduce<<<dim3(nb1), dim3(256), 0, stream>>>(emb2, lab, ws, M, nb1, atomic_mode);
    if (!atomic_mode)
        k2_reduce_partials<<<dim3(NTOT), dim3(256), 0, stream>>>(ws, nb1);
    k3_finalize<<<dim3(1), dim3(256), 0, stream>>>(ws);
    const int nb4 = 2048;
    k4_pull<<<dim3(nb4), dim3(256), 0, stream>>>(emb4, lab, ws, M, nb4);
    k5_final<<<dim3(1), dim3(64), 0, stream>>>(ws, out);
}

// Round 6
// 181.165 us; speedup vs baseline: 2.3477x; 1.0810x over previous
//
#include <hip/hip_runtime.h>

#define NUM_IDS 65
#define EDIM 32
#define NSUM (NUM_IDS * EDIM)      // 2080 per-label-dim sums
#define NTOT (NSUM + NUM_IDS)      // 2145 = sums + counts
#define LPAD 33                    // padded row for k3/k4 LDS tiles
#define ROWS 34                    // k1 row: 32 sums + count + pad; 34*4B=136B keeps 8B align
#define COPYSZ 2212                // 65*34=2210 -> pad to even for 8B-aligned copies

// ws layout (float offsets)
#define WS_MEANS   0               // 2080
#define WS_COEF    2080            // 65
#define WS_SUMS    2145            // 2145 (2080 sums then 65 counts)
#define WS_PUSH    4290
#define WS_REG     4291
#define WS_CF      4292
#define WS_C       4293
#define WS_PULLACC 4294
#define WS_PART    4352            // per-block partials [nb1][NTOT]

__global__ void k0_zero(float* __restrict__ ws) {
    int i = blockIdx.x * 256 + threadIdx.x;
    if (i < NTOT) ws[WS_SUMS + i] = 0.f;
}

// Pass 1: wave-private non-atomic LDS segment reduction with 2-deep
// software pipelining. 16 lanes per point (float2 each), 4 points per wave.
__global__ __launch_bounds__(256) void k1_reduce(const float2* __restrict__ emb2,
                                                 const int* __restrict__ lab,
                                                 float* __restrict__ ws,
                                                 int M, int nb1, int atomic_mode) {
    __shared__ float ls[4 * COPYSZ];   // 4 wave-private copies, 35.4 KB
    const int t = threadIdx.x;
    for (int j = t; j < 4 * COPYSZ; j += 256) ls[j] = 0.f;
    __syncthreads();

    const int wave = t >> 6;
    const int lane = t & 63;
    const int s = lane >> 4;           // point slot 0..3 within wave
    const int c = lane & 15;           // float2 chunk 0..15 (dims 2c,2c+1)
    float* my = ls + wave * COPYSZ;

    const long stride = (long)nb1 * 16;   // 16 points per block-iter
    const long p0 = (long)blockIdx.x * 16 + wave * 4 + s;

    // ---- prologue: prefetch iterations 0 and 1 (loads unconditional on L) ----
    int   L0 = 0, L1 = 0;
    float2 v0 = make_float2(0.f, 0.f), v1 = make_float2(0.f, 0.f);
    if (p0 < M)          { L0 = lab[p0];          v0 = emb2[p0 * 16 + c]; }
    if (p0 + stride < M) { L1 = lab[p0 + stride]; v1 = emb2[(p0 + stride) * 16 + c]; }

    for (long p = p0; p < M; p += stride) {
        // issue loads for iteration i+2 before touching LDS (hides HBM latency)
        long pp = p + 2 * stride;
        int   Ln = 0;
        float2 vn = make_float2(0.f, 0.f);
        if (pp < M) { Ln = lab[pp]; vn = emb2[pp * 16 + c]; }

        // ---- process iteration i from registers (L0, v0) ----
        const bool act = (L0 > 0);
        int key = act ? L0 : (-1 - s);   // unique negatives: inactive never collide
        int k0 = __shfl(key, 0), k1 = __shfl(key, 16);
        int k2 = __shfl(key, 32), k3 = __shfl(key, 48);
        bool col = (k0 == k1) | (k0 == k2) | (k0 == k3) |
                   (k1 == k2) | (k1 == k3) | (k2 == k3);

        const int off = L0 * ROWS + 2 * c;
        if (!col) {
            if (act) {
                float2 o = *(float2*)(my + off);
                o.x += v0.x; o.y += v0.y;
                *(float2*)(my + off) = o;
                if (c == 0) my[L0 * ROWS + 32] += 1.f;   // count
            }
        } else {
            // rare (~9%): serialize the 4 slots (DS ops are in-order per wave)
            #pragma unroll
            for (int ss = 0; ss < 4; ++ss) {
                if (s == ss && act) {
                    float2 o = *(float2*)(my + off);
                    o.x += v0.x; o.y += v0.y;
                    *(float2*)(my + off) = o;
                    if (c == 0) my[L0 * ROWS + 32] += 1.f;
                }
            }
        }

        // rotate pipeline registers
        L0 = L1; v0 = v1;
        L1 = Ln; v1 = vn;
    }
    __syncthreads();

    // Flush: sum the 4 wave copies -> per-block partials (or global atomics).
    for (int j = t; j < NTOT; j += 256) {
        int off = (j < NSUM) ? ((j >> 5) * ROWS + (j & 31))
                             : ((j - NSUM) * ROWS + 32);
        float v = ls[off] + ls[COPYSZ + off] + ls[2 * COPYSZ + off] + ls[3 * COPYSZ + off];
        if (atomic_mode) {
            if (v != 0.f) atomicAdd(&ws[WS_SUMS + j], v);
        } else {
            ws[WS_PART + (size_t)blockIdx.x * NTOT + j] = v;
        }
    }
}

// Reduce per-block partials: one block per output element j.
__global__ __launch_bounds__(256) void k2_reduce_partials(float* __restrict__ ws, int nb1) {
    const int j = blockIdx.x;       // 0..NTOT-1
    const int t = threadIdx.x;
    const float* part = ws + WS_PART;
    float acc = 0.f;
    for (int b = t; b < nb1; b += 256) acc += part[(size_t)b * NTOT + j];
    __shared__ float red[256];
    red[t] = acc;
    __syncthreads();
    for (int s = 128; s > 0; s >>= 1) {
        if (t < s) red[t] += red[t + s];
        __syncthreads();
    }
    if (t == 0) ws[WS_SUMS + j] = red[0];
}

// Means, present mask, C, push loss, reg loss, coef; zero pull accumulator.
__global__ __launch_bounds__(256) void k3_finalize(float* __restrict__ ws) {
    __shared__ float lmean[NUM_IDS * LPAD];
    __shared__ float lcnt[NUM_IDS];
    __shared__ int   lpres[NUM_IDS];
    __shared__ float red[256];
    __shared__ float red2[256];
    const int t = threadIdx.x;
    const float* sg = ws + WS_SUMS;

    if (t < NUM_IDS) {
        float cv = sg[NSUM + t];
        lcnt[t] = cv;
        lpres[t] = (t > 0 && cv > 0.f) ? 1 : 0;
    }
    __syncthreads();

    for (int j = t; j < NSUM; j += 256) {
        int cc = j >> 5, e = j & 31;
        float m = sg[j] / fmaxf(lcnt[cc], 1.f);
        ws[WS_MEANS + j] = m;
        lmean[cc * LPAD + e] = m;
    }
    if (t < NUM_IDS) ws[WS_COEF + t] = lpres[t] ? (1.f / fmaxf(lcnt[t], 1.f)) : 0.f;
    __syncthreads();

    // Push: 65*64/2 = 2080 unordered pairs.
    float psum = 0.f;
    for (int pi = t; pi < 2080; pi += 256) {
        int i = 0, rem = pi;
        while (rem >= NUM_IDS - 1 - i) { rem -= NUM_IDS - 1 - i; ++i; }
        int jj = i + 1 + rem;
        if (lpres[i] && lpres[jj]) {
            float d2 = 0.f;
            #pragma unroll
            for (int e = 0; e < EDIM; ++e) {
                float d = lmean[i * LPAD + e] - lmean[jj * LPAD + e];
                d2 += d * d;
            }
            float pd = sqrtf(d2);
            float h = fmaxf(2.0f * 1.5f - pd, 0.f);  // 2*DELTA_PUSH = 3.0
            psum += h * h;
        }
    }
    // Reg: norm of present means.
    float rsum = 0.f;
    if (t < NUM_IDS && lpres[t]) {
        float m2 = 0.f;
        #pragma unroll
        for (int e = 0; e < EDIM; ++e) { float m = lmean[t * LPAD + e]; m2 += m * m; }
        rsum = sqrtf(m2);
    }
    red[t] = psum; red2[t] = rsum;
    __syncthreads();
    for (int s = 128; s > 0; s >>= 1) {
        if (t < s) { red[t] += red[t + s]; red2[t] += red2[t + s]; }
        __syncthreads();
    }
    if (t == 0) {
        int C = 0;
        for (int cc = 1; cc < NUM_IDS; ++cc) C += lpres[cc];
        float Cf = fmaxf((float)C, 1.f);
        long np = (long)C * (C - 1) / 2;
        ws[WS_PUSH] = (np > 0) ? red[0] / (float)np : 0.f;
        ws[WS_REG]  = red2[0] / Cf;
        ws[WS_CF]   = Cf;
        ws[WS_C]    = (float)C;
        ws[WS_PULLACC] = 0.f;
    }
}

// Pass 2: hinged pull distances; per-block scalar contribution.
__global__ __launch_bounds__(256) void k4_pull(const float4* __restrict__ emb4,
                                               const int* __restrict__ lab,
                                               float* __restrict__ ws,
                                               int M, int nb4) {
    __shared__ float lmean[NUM_IDS * LPAD];
    __shared__ float lcoef[NUM_IDS];
    __shared__ float lpull[NUM_IDS];
    __shared__ float red[NUM_IDS];
    const int t = threadIdx.x;
    for (int j = t; j < NSUM; j += 256) lmean[(j >> 5) * LPAD + (j & 31)] = ws[WS_MEANS + j];
    if (t < NUM_IDS) { lcoef[t] = ws[WS_COEF + t]; lpull[t] = 0.f; }
    __syncthreads();

    const int c = t & 7;
    const int stride = nb4 * 32;   // 256 threads / 8 = 32 points per block-iter
    for (int p = blockIdx.x * 32 + (t >> 3); p < M; p += stride) {
        int L = lab[p];
        float d2 = 0.f;
        if (L > 0) {
            float4 v = emb4[(size_t)p * 8 + c];
            int base = L * LPAD + c * 4;
            float dx = v.x - lmean[base + 0];
            float dy = v.y - lmean[base + 1];
            float dz = v.z - lmean[base + 2];
            float dw = v.w - lmean[base + 3];
            d2 = dx * dx + dy * dy + dz * dz + dw * dw;
        }
        d2 += __shfl_xor(d2, 1);
        d2 += __shfl_xor(d2, 2);
        d2 += __shfl_xor(d2, 4);
        if (c == 0 && L > 0 && d2 > 0.f) {
            float dist = sqrtf(d2);
            float h = fmaxf(dist - 0.5f, 0.f);   // DELTA_PULL = 0.5
            atomicAdd(&lpull[L], h * h);
        }
    }
    __syncthreads();
    if (t < NUM_IDS) red[t] = lpull[t] * lcoef[t];
    __syncthreads();
    if (t == 0) {
        float s = 0.f;
        for (int cc = 1; cc < NUM_IDS; ++cc) s += red[cc];
        atomicAdd(&ws[WS_PULLACC], s);
    }
}

__global__ void k5_final(const float* __restrict__ ws, float* __restrict__ out) {
    if (threadIdx.x == 0) {
        float C = ws[WS_C];
        float total = 0.f;
        if (C > 0.f) {
            total = ws[WS_PULLACC] / ws[WS_CF]   // ALPHA = 1
                  + ws[WS_PUSH]                  // BETA = 1
                  + 0.001f * ws[WS_REG];         // GAMMA = 0.001
        }
        out[0] = total;
    }
}

extern "C" void kernel_launch(void* const* d_in, const int* in_sizes, int n_in,
                              void* d_out, int out_size, void* d_ws, size_t ws_size,
                              hipStream_t stream) {
    const float2* emb2 = (const float2*)d_in[0];
    const float4* emb4 = (const float4*)d_in[0];
    const int* lab = (const int*)d_in[1];
    float* ws = (float*)d_ws;
    float* out = (float*)d_out;
    const int M = in_sizes[1];

    // Size pass-1 grid to available workspace; fall back to global atomics if tiny.
    long ws_floats = (long)(ws_size / 4);
    long avail = ws_floats - WS_PART - 64;
    int nb1 = (int)(avail / NTOT);
    if (nb1 > 1024) nb1 = 1024;
    int atomic_mode = (nb1 < 8) ? 1 : 0;
    if (atomic_mode) {
        nb1 = 1024;
        k0_zero<<<dim3(9), dim3(256), 0, stream>>>(ws);
    }

    k1_reduce<<<dim3(nb1), dim3(256), 0, stream>>>(emb2, lab, ws, M, nb1, atomic_mode);
    if (!atomic_mode)
        k2_reduce_partials<<<dim3(NTOT), dim3(256), 0, stream>>>(ws, nb1);
    k3_finalize<<<dim3(1), dim3(256), 0, stream>>>(ws);
    const int nb4 = 2048;
    k4_pull<<<dim3(nb4), dim3(256), 0, stream>>>(emb4, lab, ws, M, nb4);
    k5_final<<<dim3(1), dim3(64), 0, stream>>>(ws, out);
}